// Round 5
// baseline (414.250 us; speedup 1.0000x reference)
//
#include <hip/hip_runtime.h>
#include <hip/hip_cooperative_groups.h>
#include <stdint.h>

namespace cg = cooperative_groups;

#define PRIME 1000003u
#define NORD  1000002u
#define KCH   16
#define BATCH 4
#define NPATCH 784
#define LLEN  9
#define IPMAX 9000        // |<x,y>| <= 20*50*9
#define TBLN  (2*IPMAX+1)
#define NDEC  (KCH*BATCH*NPATCH)   // 50176

// Barrett: M = floor(2^41/p) = 2199016; exact for t < 2^40 with one cond-sub.
__device__ __forceinline__ uint32_t mmul(uint32_t a, uint32_t b) {
    uint64_t t = (uint64_t)a * (uint64_t)b;
    uint32_t q = (uint32_t)((t * 2199016ull) >> 41);
    uint32_t r = (uint32_t)t - q * PRIME;
    return (r >= PRIME) ? r - PRIME : r;
}

__device__ __forceinline__ uint32_t mpow(uint32_t base, uint32_t exp) {
    uint32_t r = 1u, b = base;
    while (exp) {
        if (exp & 1u) r = mmul(r, b);
        b = mmul(b, b);
        exp >>= 1;
    }
    return r;
}

struct Params {
    const int *ct0, *cts, *y, *sk_y;
    const float *bias1, *bn1_g, *bn1_b, *bn1_m, *bn1_v;
    const float *conv2_w, *conv2_b, *bn2_g, *bn2_b, *bn2_m, *bn2_v;
    const float *conv3_w, *conv3_b, *bn3_g, *bn3_b, *bn3_m, *bn3_v;
    const float *fc1_w, *fc1_b, *fc2_w, *fc2_b;
    const int *g_in;
    float *out;
    int *table;            // p int32 entries
    float *featr;          // [4][16][28][28] post bn1+relu
    float *s2g;            // [4][32][7][7]
    float *s3g;            // [4][576]
    float *h;              // [4][128]
};

// One cooperative dispatch, 256 blocks x 256 threads (1 block/CU, co-resident).
__global__ void __launch_bounds__(256) fused(Params p) {
    cg::grid_group grid = cg::this_grid();
    const int bid  = blockIdx.x;
    const int tid  = threadIdx.x;
    const int gtid = bid * 256 + tid;
    const int lane = tid & 63;

    __shared__ union {
        struct { float s1p[16][16][16]; float w[144]; float co[196]; } c2; // 17.7 KB
        struct { float s2p[32][9][9];   float w[288]; float co[49];  } c3; // 11.7 KB
    } sh;

    // ---- P0: dlog table: table[g^e mod p] = e, e in [-9000,9000] ----------
    if (gtid < TBLN) {
        int es = gtid - IPMAX;
        uint32_t exp = (es >= 0) ? (uint32_t)es : (uint32_t)(es + (int)NORD);
        p.table[mpow((uint32_t)p.g_in[0], exp)] = es;
    }
    __threadfence();
    grid.sync();

    // ---- P1: IPFE decrypt + dlog + bias1 + bn1 + relu ---------------------
    if (gtid < NDEC) {
        int k = gtid / (BATCH * NPATCH);
        int r = gtid % (BATCH * NPATCH);
        int b = r / NPATCH;
        int j = r % NPATCH;

        const int* crow = p.cts + ((b * NPATCH) + j) * LLEN;
        const int* yrow = p.y + k * LLEN;

        uint32_t num_p = 1u, num_n = 1u;
#pragma unroll
        for (int i = 0; i < LLEN; i++) {
            int yi = yrow[i];                       // wave-uniform
            uint32_t c = (uint32_t)crow[i];
            if (yi > 0)       num_p = mmul(num_p, mpow(c, (uint32_t)yi));
            else if (yi < 0)  num_n = mmul(num_n, mpow(c, (uint32_t)(-yi)));
        }
        uint32_t den = mpow((uint32_t)p.ct0[b * NPATCH + j], (uint32_t)p.sk_y[k]);
        den = mmul(den, num_n);
        uint32_t val = mmul(num_p, mpow(den, PRIME - 2u));  // const exp: unrolls

        int ip = p.table[val];
        float sc = p.bn1_g[k] * rsqrtf(p.bn1_v[k] + 1e-5f);
        float shf = (p.bias1[k] - p.bn1_m[k]) * sc + p.bn1_b[k];
        float v_ = fmaf((float)ip, sc * 1e-4f, shf);
        p.featr[((b * KCH) + k) * NPATCH + j] = fmaxf(v_, 0.0f);
    }
    __threadfence();
    grid.sync();

    // ---- P2: pool(28->14) + conv2 + bn2 + relu + pool(14->7), 128 blocks --
    if (bid < 128) {
        const int b  = bid >> 5;
        const int oc = bid & 31;

        for (int i = tid; i < 16 * 16 * 16; i += 256)
            ((float*)sh.c2.s1p)[i] = 0.0f;
        if (tid < 144) sh.c2.w[tid] = p.conv2_w[oc * 144 + tid];
        __syncthreads();
        for (int i = tid; i < 16 * 196; i += 256) {
            int ic = i / 196, pos = i % 196;
            int yy = pos / 14, xx = pos % 14;
            const float* fp = p.featr + ((b * 16 + ic) * 784) + (2 * yy) * 28 + 2 * xx;
            sh.c2.s1p[ic][yy + 1][xx + 1] =
                fmaxf(fmaxf(fp[0], fp[1]), fmaxf(fp[28], fp[29]));
        }
        __syncthreads();

        if (tid < 196) {
            int oh = tid / 14, ow = tid % 14;
            float a0 = 0.0f, a1 = 0.0f, a2 = 0.0f;
#pragma unroll
            for (int ic = 0; ic < 16; ic++) {
                const float* wp = &sh.c2.w[ic * 9];
                const float* sp = &sh.c2.s1p[ic][oh][ow];
                a0 = fmaf(sp[0],  wp[0], fmaf(sp[1],  wp[1], fmaf(sp[2],  wp[2], a0)));
                a1 = fmaf(sp[16], wp[3], fmaf(sp[17], wp[4], fmaf(sp[18], wp[5], a1)));
                a2 = fmaf(sp[32], wp[6], fmaf(sp[33], wp[7], fmaf(sp[34], wp[8], a2)));
            }
            float sc = p.bn2_g[oc] * rsqrtf(p.bn2_v[oc] + 1e-5f);
            float shf = p.bn2_b[oc] - p.bn2_m[oc] * sc;
            sh.c2.co[tid] = fmaxf((a0 + a1 + a2 + p.conv2_b[oc]) * sc + shf, 0.0f);
        }
        __syncthreads();

        if (tid < 49) {
            int oh = tid / 7, ow = tid % 7;
            const float* c0 = &sh.c2.co[(2 * oh) * 14 + 2 * ow];
            p.s2g[((b * 32 + oc) * 49) + tid] =
                fmaxf(fmaxf(c0[0], c0[1]), fmaxf(c0[14], c0[15]));
        }
    }
    __threadfence();
    grid.sync();

    // ---- P3: conv3 + bn3 + relu + pool(7->3), 256 blocks (b,oc) -----------
    {
        const int b  = bid >> 6;
        const int oc = bid & 63;

        for (int i = tid; i < 32 * 81; i += 256)
            ((float*)sh.c3.s2p)[i] = 0.0f;
        for (int i = tid; i < 288; i += 256)          // FIX: was `if (tid<288)`
            sh.c3.w[i] = p.conv3_w[oc * 288 + i];
        __syncthreads();
        for (int i = tid; i < 32 * 49; i += 256) {
            int ic = i / 49, pos = i % 49;
            sh.c3.s2p[ic][pos / 7 + 1][pos % 7 + 1] = p.s2g[(b * 32 + ic) * 49 + pos];
        }
        __syncthreads();

        if (tid < 49) {
            int oh = tid / 7, ow = tid % 7;
            float a0 = 0.0f, a1 = 0.0f, a2 = 0.0f;
#pragma unroll
            for (int ic = 0; ic < 32; ic++) {
                const float* wp = &sh.c3.w[ic * 9];
                const float* sp = &sh.c3.s2p[ic][oh][ow];
                a0 = fmaf(sp[0],  wp[0], fmaf(sp[1],  wp[1], fmaf(sp[2],  wp[2], a0)));
                a1 = fmaf(sp[9],  wp[3], fmaf(sp[10], wp[4], fmaf(sp[11], wp[5], a1)));
                a2 = fmaf(sp[18], wp[6], fmaf(sp[19], wp[7], fmaf(sp[20], wp[8], a2)));
            }
            float sc = p.bn3_g[oc] * rsqrtf(p.bn3_v[oc] + 1e-5f);
            float shf = p.bn3_b[oc] - p.bn3_m[oc] * sc;
            sh.c3.co[tid] = fmaxf((a0 + a1 + a2 + p.conv3_b[oc]) * sc + shf, 0.0f);
        }
        __syncthreads();

        if (tid < 9) {
            int oh = tid / 3, ow = tid % 3;
            const float* c0 = &sh.c3.co[(2 * oh) * 7 + 2 * ow];
            p.s3g[b * 576 + oc * 9 + tid] =
                fmaxf(fmaxf(c0[0], c0[1]), fmaxf(c0[7], c0[8]));
        }
    }
    __threadfence();
    grid.sync();

    // ---- P4: fc1 (576->128) + relu; one wave per (b,o), coalesced ---------
    {
        const int wid = gtid >> 6;          // 0..1023
        if (wid < BATCH * 128) {
            const int b = wid >> 7, o = wid & 127;
            const float* w = p.fc1_w + o * 576;
            const float* x = p.s3g + b * 576;
            float acc = 0.0f;
#pragma unroll
            for (int j = 0; j < 9; j++)      // 576 = 9*64, coalesced per step
                acc = fmaf(x[j * 64 + lane], w[j * 64 + lane], acc);
#pragma unroll
            for (int off = 32; off; off >>= 1) acc += __shfl_down(acc, off);
            if (lane == 0)
                p.h[b * 128 + o] = fmaxf(acc + p.fc1_b[o], 0.0f);
        }
    }
    __threadfence();
    grid.sync();

    // ---- P5: fc2 (128->10); one wave per (b,o) ----------------------------
    {
        const int wid = gtid >> 6;
        if (wid < BATCH * 10) {
            const int b = wid / 10, o = wid % 10;
            const float* w = p.fc2_w + o * 128;
            const float* x = p.h + b * 128;
            float acc = fmaf(x[lane], w[lane], 0.0f);
            acc = fmaf(x[64 + lane], w[64 + lane], acc);
#pragma unroll
            for (int off = 32; off; off >>= 1) acc += __shfl_down(acc, off);
            if (lane == 0) p.out[b * 10 + o] = acc + p.fc2_b[o];
        }
    }
}

extern "C" void kernel_launch(void* const* d_in, const int* in_sizes, int n_in,
                              void* d_out, int out_size, void* d_ws, size_t ws_size,
                              hipStream_t stream) {
    char* ws = (char*)d_ws;
    Params prm;
    prm.ct0     = (const int*)d_in[0];
    prm.cts     = (const int*)d_in[1];
    prm.y       = (const int*)d_in[2];
    prm.sk_y    = (const int*)d_in[3];
    prm.bias1   = (const float*)d_in[4];
    prm.bn1_g   = (const float*)d_in[5];
    prm.bn1_b   = (const float*)d_in[6];
    prm.bn1_m   = (const float*)d_in[7];
    prm.bn1_v   = (const float*)d_in[8];
    prm.conv2_w = (const float*)d_in[9];
    prm.conv2_b = (const float*)d_in[10];
    prm.bn2_g   = (const float*)d_in[11];
    prm.bn2_b   = (const float*)d_in[12];
    prm.bn2_m   = (const float*)d_in[13];
    prm.bn2_v   = (const float*)d_in[14];
    prm.conv3_w = (const float*)d_in[15];
    prm.conv3_b = (const float*)d_in[16];
    prm.bn3_g   = (const float*)d_in[17];
    prm.bn3_b   = (const float*)d_in[18];
    prm.bn3_m   = (const float*)d_in[19];
    prm.bn3_v   = (const float*)d_in[20];
    prm.fc1_w   = (const float*)d_in[21];
    prm.fc1_b   = (const float*)d_in[22];
    prm.fc2_w   = (const float*)d_in[23];
    prm.fc2_b   = (const float*)d_in[24];
    prm.g_in    = (const int*)d_in[25];
    prm.out     = (float*)d_out;

    // Workspace layout (bytes):
    //   [0,        4000256)  int32 dlog table (p entries)
    //   [4000256,  4200960)  float featr [4][16][28][28]
    //   [4200960,  4226048)  float s2g   [4][32][7][7]
    //   [4226048,  4235264)  float s3g   [4][576]
    //   [4235264,  4237312)  float h     [4][128]
    prm.table = (int*)ws;
    prm.featr = (float*)(ws + 4000256);
    prm.s2g   = (float*)(ws + 4200960);
    prm.s3g   = (float*)(ws + 4226048);
    prm.h     = (float*)(ws + 4235264);

    void* args[] = { (void*)&prm };
    hipLaunchCooperativeKernel((const void*)fused, dim3(256), dim3(256),
                               args, 0, stream);
}

// Round 6
// 156.736 us; speedup vs baseline: 2.6430x; 2.6430x over previous
//
#include <hip/hip_runtime.h>
#include <stdint.h>

#define PRIME 1000003u
#define NORD  1000002u
#define KCH   16
#define BATCH 4
#define NPATCH 784
#define LLEN  9
#define IPMAX 9000          // |<x,y>| <= 20*50*9
#define NDEC  (KCH*BATCH*NPATCH)   // 50176
#define MBABY 512
#define NGIANT 36           // 35*512+488 >= 18000
#define HSLOTS 2048
#define HEMPTY 0xFFFFFFFFu

// Barrett: M = floor(2^41/p) = 2199016; exact for t < 2^40 with one cond-sub.
__device__ __forceinline__ uint32_t mmul(uint32_t a, uint32_t b) {
    uint64_t t = (uint64_t)a * (uint64_t)b;
    uint32_t q = (uint32_t)((t * 2199016ull) >> 41);
    uint32_t r = (uint32_t)t - q * PRIME;
    return (r >= PRIME) ? r - PRIME : r;
}

__device__ __forceinline__ uint32_t mpow(uint32_t base, uint32_t exp) {
    uint32_t r = 1u, b = base;
    while (exp) {
        if (exp & 1u) r = mmul(r, b);
        b = mmul(b, b);
        exp >>= 1;
    }
    return r;
}

// ---------------- Kernel 1: IPFE decrypt + LDS-BSGS dlog + bias1+bn1+relu ---
// featr: [B][16][28][28] post bn1+relu. 196 blocks x 256 threads.
__global__ void __launch_bounds__(256) decrypt_dlog(
    const int* __restrict__ ct0, const int* __restrict__ cts,
    const int* __restrict__ y, const int* __restrict__ sk_y,
    const float* __restrict__ bias1,
    const float* __restrict__ bn1_g, const float* __restrict__ bn1_b,
    const float* __restrict__ bn1_m, const float* __restrict__ bn1_v,
    const int* __restrict__ g_in, float* __restrict__ featr) {
    const int tid = threadIdx.x;
    __shared__ uint32_t hash[HSLOTS];

    const uint32_t g = (uint32_t)g_in[0];

    // build baby-step hash: key = g^r (r<512), packed (key<<9)|r
    for (int i = tid; i < HSLOTS; i += 256) hash[i] = HEMPTY;
    __syncthreads();
    for (int r = tid; r < MBABY; r += 256) {
        uint32_t key = mpow(g, (uint32_t)r);
        uint32_t h = (key * 0x9E3779B1u) >> 21;      // top 11 bits -> [0,2048)
        uint32_t packed = (key << 9) | (uint32_t)r;  // key<2^20 -> fits
        while (atomicCAS(&hash[h], HEMPTY, packed) != HEMPTY)
            h = (h + 1) & (HSLOTS - 1);
    }
    __syncthreads();

    const int gtid = blockIdx.x * 256 + tid;
    if (gtid >= NDEC) return;
    int k = gtid / (BATCH * NPATCH);
    int r = gtid % (BATCH * NPATCH);
    int b = r / NPATCH;
    int j = r % NPATCH;

    const int* crow = cts + ((b * NPATCH) + j) * LLEN;
    const int* yrow = y + k * LLEN;

    uint32_t num_p = 1u, num_n = 1u;
#pragma unroll
    for (int i = 0; i < LLEN; i++) {
        int yi = yrow[i];                            // wave-uniform (mostly)
        uint32_t c = (uint32_t)crow[i];
        if (yi > 0)       num_p = mmul(num_p, mpow(c, (uint32_t)yi));
        else if (yi < 0)  num_n = mmul(num_n, mpow(c, (uint32_t)(-yi)));
    }
    uint32_t den = mpow((uint32_t)ct0[b * NPATCH + j], (uint32_t)sk_y[k]);
    den = mmul(den, num_n);
    uint32_t val = mmul(num_p, mpow(den, PRIME - 2u));  // = g^ip, |ip|<=9000

    // BSGS: val' = val * g^9000 = g^e', e' in [0,18000]; e' = 512q + r
    uint32_t cur = mmul(val, mpow(g, IPMAX));
    const uint32_t gim = mpow(g, NORD - MBABY);         // g^-512
    int e = 0;
    bool found = false;
    for (int q = 0; q < NGIANT; q++) {
        if (!found) {
            uint32_t hh = (cur * 0x9E3779B1u) >> 21;
            uint32_t v;
            while ((v = hash[hh]) != HEMPTY) {
                if ((v >> 9) == cur) { e = q * MBABY + (int)(v & 511u); found = true; break; }
                hh = (hh + 1) & (HSLOTS - 1);
            }
        }
        cur = mmul(cur, gim);
    }
    int ip = e - IPMAX;

    float sc = bn1_g[k] * rsqrtf(bn1_v[k] + 1e-5f);
    float shf = (bias1[k] - bn1_m[k]) * sc + bn1_b[k];
    float v_ = fmaf((float)ip, sc * 1e-4f, shf);
    featr[((b * KCH) + k) * NPATCH + j] = fmaxf(v_, 0.0f);
}

// ---------------- Kernel 2: pool(28->14) + conv2 + bn2 + relu + pool(14->7) -
// block = (b, oc): 128 blocks x 256 threads. s2g: [B][32][7][7]
__global__ void __launch_bounds__(256) conv2_k(
    const float* __restrict__ featr,
    const float* __restrict__ conv2_w, const float* __restrict__ conv2_b,
    const float* __restrict__ bn2_g, const float* __restrict__ bn2_b,
    const float* __restrict__ bn2_m, const float* __restrict__ bn2_v,
    float* __restrict__ s2g) {
    const int b  = blockIdx.x >> 5;
    const int oc = blockIdx.x & 31;
    const int tid = threadIdx.x;

    __shared__ float s1p[16][16][16];   // padded halo of zeros, 16 KB
    __shared__ float w[16 * 9];
    __shared__ float co[196];

    for (int i = tid; i < 16 * 16 * 16; i += 256)
        ((float*)s1p)[i] = 0.0f;
    if (tid < 144) w[tid] = conv2_w[oc * 144 + tid];
    __syncthreads();
    for (int i = tid; i < 16 * 196; i += 256) {
        int ic = i / 196, pos = i % 196;
        int yy = pos / 14, xx = pos % 14;
        const float* fp = featr + ((b * 16 + ic) * 784) + (2 * yy) * 28 + 2 * xx;
        s1p[ic][yy + 1][xx + 1] = fmaxf(fmaxf(fp[0], fp[1]), fmaxf(fp[28], fp[29]));
    }
    __syncthreads();

    if (tid < 196) {
        int oh = tid / 14, ow = tid % 14;
        float a0 = 0.0f, a1 = 0.0f, a2 = 0.0f;
#pragma unroll
        for (int ic = 0; ic < 16; ic++) {
            const float* wp = &w[ic * 9];
            const float* sp = &s1p[ic][oh][ow];
            a0 = fmaf(sp[0],  wp[0], fmaf(sp[1],  wp[1], fmaf(sp[2],  wp[2], a0)));
            a1 = fmaf(sp[16], wp[3], fmaf(sp[17], wp[4], fmaf(sp[18], wp[5], a1)));
            a2 = fmaf(sp[32], wp[6], fmaf(sp[33], wp[7], fmaf(sp[34], wp[8], a2)));
        }
        float sc = bn2_g[oc] * rsqrtf(bn2_v[oc] + 1e-5f);
        float shf = bn2_b[oc] - bn2_m[oc] * sc;
        co[tid] = fmaxf((a0 + a1 + a2 + conv2_b[oc]) * sc + shf, 0.0f);
    }
    __syncthreads();

    if (tid < 49) {
        int oh = tid / 7, ow = tid % 7;
        const float* c0 = &co[(2 * oh) * 14 + 2 * ow];
        s2g[((b * 32 + oc) * 49) + tid] =
            fmaxf(fmaxf(c0[0], c0[1]), fmaxf(c0[14], c0[15]));
    }
}

// ---------------- Kernel 3: conv3 + bn3 + relu + pool(7->3) -----------------
// block = (b, oc): 256 blocks x 64 threads. s3g: [B][576] flat [64][3][3]
__global__ void __launch_bounds__(64) conv3_k(
    const float* __restrict__ s2g,
    const float* __restrict__ conv3_w, const float* __restrict__ conv3_b,
    const float* __restrict__ bn3_g, const float* __restrict__ bn3_b,
    const float* __restrict__ bn3_m, const float* __restrict__ bn3_v,
    float* __restrict__ s3g) {
    const int b  = blockIdx.x >> 6;
    const int oc = blockIdx.x & 63;
    const int tid = threadIdx.x;

    __shared__ float s2p[32][9][9];    // padded, 10.1 KB
    __shared__ float w[32 * 9];
    __shared__ float co[49];

    for (int i = tid; i < 32 * 81; i += 64)
        ((float*)s2p)[i] = 0.0f;
    for (int i = tid; i < 288; i += 64) w[i] = conv3_w[oc * 288 + i];
    __syncthreads();
    for (int i = tid; i < 32 * 49; i += 64) {
        int ic = i / 49, pos = i % 49;
        s2p[ic][pos / 7 + 1][pos % 7 + 1] = s2g[((b * 32 + ic) * 49) + pos];
    }
    __syncthreads();

    if (tid < 49) {
        int oh = tid / 7, ow = tid % 7;
        float a0 = 0.0f, a1 = 0.0f, a2 = 0.0f;
#pragma unroll
        for (int ic = 0; ic < 32; ic++) {
            const float* wp = &w[ic * 9];
            const float* sp = &s2p[ic][oh][ow];
            a0 = fmaf(sp[0],  wp[0], fmaf(sp[1],  wp[1], fmaf(sp[2],  wp[2], a0)));
            a1 = fmaf(sp[9],  wp[3], fmaf(sp[10], wp[4], fmaf(sp[11], wp[5], a1)));
            a2 = fmaf(sp[18], wp[6], fmaf(sp[19], wp[7], fmaf(sp[20], wp[8], a2)));
        }
        float sc = bn3_g[oc] * rsqrtf(bn3_v[oc] + 1e-5f);
        float shf = bn3_b[oc] - bn3_m[oc] * sc;
        co[tid] = fmaxf((a0 + a1 + a2 + conv3_b[oc]) * sc + shf, 0.0f);
    }
    __syncthreads();

    if (tid < 9) {
        int oh = tid / 3, ow = tid % 3;
        const float* c0 = &co[(2 * oh) * 7 + 2 * ow];
        s3g[b * 576 + oc * 9 + tid] = fmaxf(fmaxf(c0[0], c0[1]), fmaxf(c0[7], c0[8]));
    }
}

// ---------------- Kernel 4: fc1 + relu + fc2, wave-coalesced ----------------
// 4 blocks x 1024 threads (16 waves: 8 fc1-outputs each; 10 waves do fc2).
__global__ void __launch_bounds__(1024) fc_k(
    const float* __restrict__ s3g,
    const float* __restrict__ fc1_w, const float* __restrict__ fc1_b,
    const float* __restrict__ fc2_w, const float* __restrict__ fc2_b,
    float* __restrict__ out) {
    const int b = blockIdx.x;
    const int tid = threadIdx.x;
    const int wid = tid >> 6, lane = tid & 63;
    __shared__ float s3[576];
    __shared__ float h[128];

    for (int i = tid; i < 576; i += 1024) s3[i] = s3g[b * 576 + i];
    __syncthreads();

#pragma unroll
    for (int oo = 0; oo < 8; oo++) {
        int o = wid * 8 + oo;
        const float* w = fc1_w + o * 576;
        float acc = 0.0f;
#pragma unroll
        for (int jj = 0; jj < 9; jj++)     // lanes across 576: coalesced
            acc = fmaf(s3[jj * 64 + lane], w[jj * 64 + lane], acc);
#pragma unroll
        for (int off = 32; off; off >>= 1) acc += __shfl_down(acc, off);
        if (lane == 0) h[o] = fmaxf(acc + fc1_b[o], 0.0f);
    }
    __syncthreads();

    if (wid < 10) {
        const float* w = fc2_w + wid * 128;
        float acc = fmaf(s3[0] * 0.0f + h[lane], w[lane], 0.0f);   // h[lane]
        acc = fmaf(h[64 + lane], w[64 + lane], acc);
#pragma unroll
        for (int off = 32; off; off >>= 1) acc += __shfl_down(acc, off);
        if (lane == 0) out[b * 10 + wid] = acc + fc2_b[wid];
    }
}

extern "C" void kernel_launch(void* const* d_in, const int* in_sizes, int n_in,
                              void* d_out, int out_size, void* d_ws, size_t ws_size,
                              hipStream_t stream) {
    const int*   ct0    = (const int*)d_in[0];
    const int*   cts    = (const int*)d_in[1];
    const int*   y      = (const int*)d_in[2];
    const int*   sk_y   = (const int*)d_in[3];
    const float* bias1  = (const float*)d_in[4];
    const float* bn1_g  = (const float*)d_in[5];
    const float* bn1_b  = (const float*)d_in[6];
    const float* bn1_m  = (const float*)d_in[7];
    const float* bn1_v  = (const float*)d_in[8];
    const float* conv2_w = (const float*)d_in[9];
    const float* conv2_b = (const float*)d_in[10];
    const float* bn2_g  = (const float*)d_in[11];
    const float* bn2_b  = (const float*)d_in[12];
    const float* bn2_m  = (const float*)d_in[13];
    const float* bn2_v  = (const float*)d_in[14];
    const float* conv3_w = (const float*)d_in[15];
    const float* conv3_b = (const float*)d_in[16];
    const float* bn3_g  = (const float*)d_in[17];
    const float* bn3_b  = (const float*)d_in[18];
    const float* bn3_m  = (const float*)d_in[19];
    const float* bn3_v  = (const float*)d_in[20];
    const float* fc1_w  = (const float*)d_in[21];
    const float* fc1_b  = (const float*)d_in[22];
    const float* fc2_w  = (const float*)d_in[23];
    const float* fc2_b  = (const float*)d_in[24];
    const int*   g_in   = (const int*)d_in[25];
    float* out = (float*)d_out;

    // Workspace (bytes): featr [0,200704), s2g [200704,225792), s3g [225792,235008)
    char* ws = (char*)d_ws;
    float* featr = (float*)ws;
    float* s2g   = (float*)(ws + 200704);
    float* s3g   = (float*)(ws + 225792);

    decrypt_dlog<<<NDEC / 256, 256, 0, stream>>>(
        ct0, cts, y, sk_y, bias1, bn1_g, bn1_b, bn1_m, bn1_v, g_in, featr);

    conv2_k<<<BATCH * 32, 256, 0, stream>>>(
        featr, conv2_w, conv2_b, bn2_g, bn2_b, bn2_m, bn2_v, s2g);

    conv3_k<<<BATCH * 64, 64, 0, stream>>>(
        s2g, conv3_w, conv3_b, bn3_g, bn3_b, bn3_m, bn3_v, s3g);

    fc_k<<<BATCH, 1024, 0, stream>>>(s3g, fc1_w, fc1_b, fc2_w, fc2_b, out);
}

// Round 7
// 143.109 us; speedup vs baseline: 2.8946x; 1.0952x over previous
//
#include <hip/hip_runtime.h>
#include <stdint.h>

#define PRIME 1000003u
#define NORD  1000002u
#define KCH   16
#define BATCH 4
#define NPATCH 784
#define LLEN  9
#define IPMAX 9000          // |<x,y>| <= 20*50*9
#define TBLN  (2*IPMAX+1)
#define NDEC  (KCH*BATCH*NPATCH)   // 50176

// Barrett: M = floor(2^41/p) = 2199016; exact for t < 2^40 with one cond-sub.
__device__ __forceinline__ uint32_t mmul(uint32_t a, uint32_t b) {
    uint64_t t = (uint64_t)a * (uint64_t)b;
    uint32_t q = (uint32_t)((t * 2199016ull) >> 41);
    uint32_t r = (uint32_t)t - q * PRIME;
    return (r >= PRIME) ? r - PRIME : r;
}

__device__ __forceinline__ uint32_t mpow(uint32_t base, uint32_t exp) {
    uint32_t r = 1u, b = base;
    while (exp) {
        if (exp & 1u) r = mmul(r, b);
        b = mmul(b, b);
        exp >>= 1;
    }
    return r;
}

// ---------------- Kernel 1: dlog lookup table -------------------------------
// table[g^e mod p] = e for e in [-9000,9000]. Only queried entries are ever
// written (decrypted values are guaranteed to be g^e with |e|<=9000), so the
// 0xAA poison elsewhere is never read.
__global__ void build_table(const int* __restrict__ g_in, int* __restrict__ table) {
    int e = blockIdx.x * blockDim.x + threadIdx.x;
    if (e >= TBLN) return;
    int es = e - IPMAX;
    uint32_t exp = (es >= 0) ? (uint32_t)es : (uint32_t)(es + (int)NORD);
    table[mpow((uint32_t)g_in[0], exp)] = es;
}

// ---------------- Kernel 2: IPFE decrypt + table dlog + bias1+bn1+relu ------
// featr: [B][16][28][28] post bn1+relu. 196 blocks x 256 threads.
__global__ void __launch_bounds__(256) decrypt(
    const int* __restrict__ ct0, const int* __restrict__ cts,
    const int* __restrict__ y, const int* __restrict__ sk_y,
    const float* __restrict__ bias1,
    const float* __restrict__ bn1_g, const float* __restrict__ bn1_b,
    const float* __restrict__ bn1_m, const float* __restrict__ bn1_v,
    const int* __restrict__ table, float* __restrict__ featr) {
    int gtid = blockIdx.x * 256 + threadIdx.x;
    if (gtid >= NDEC) return;
    // 3136 = 49 waves exactly -> k is wave-uniform; force scalarization.
    int k = __builtin_amdgcn_readfirstlane(gtid / (BATCH * NPATCH));
    int r = gtid % (BATCH * NPATCH);
    int b = r / NPATCH;
    int j = r % NPATCH;

    const int* crow = cts + ((b * NPATCH) + j) * LLEN;
    const int* yrow = y + k * LLEN;

    uint32_t num_p = 1u, num_n = 1u;
#pragma unroll
    for (int i = 0; i < LLEN; i++) {
        int yi = yrow[i];                  // scalar load; uniform branch below
        uint32_t c = (uint32_t)crow[i];
        if (yi > 0)       num_p = mmul(num_p, mpow(c, (uint32_t)yi));
        else if (yi < 0)  num_n = mmul(num_n, mpow(c, (uint32_t)(-yi)));
    }
    uint32_t den = mpow((uint32_t)ct0[b * NPATCH + j], (uint32_t)sk_y[k]);
    den = mmul(den, num_n);
    uint32_t val = mmul(num_p, mpow(den, PRIME - 2u));  // const exp: unrolls

    int ip = table[val];                   // guaranteed hit, |ip|<=9000

    float sc = bn1_g[k] * rsqrtf(bn1_v[k] + 1e-5f);
    float shf = (bias1[k] - bn1_m[k]) * sc + bn1_b[k];
    float v_ = fmaf((float)ip, sc * 1e-4f, shf);
    featr[((b * KCH) + k) * NPATCH + j] = fmaxf(v_, 0.0f);
}

// ---------------- Kernel 3: pool(28->14) + conv2 + bn2 + relu + pool(14->7) -
// block = (b, oc): 128 blocks x 256 threads. s2g: [B][32][7][7]
__global__ void __launch_bounds__(256) conv2_k(
    const float* __restrict__ featr,
    const float* __restrict__ conv2_w, const float* __restrict__ conv2_b,
    const float* __restrict__ bn2_g, const float* __restrict__ bn2_b,
    const float* __restrict__ bn2_m, const float* __restrict__ bn2_v,
    float* __restrict__ s2g) {
    const int b  = blockIdx.x >> 5;
    const int oc = blockIdx.x & 31;
    const int tid = threadIdx.x;

    __shared__ float s1p[16][16][16];   // padded halo of zeros, 16 KB
    __shared__ float w[16 * 9];
    __shared__ float co[196];

    for (int i = tid; i < 16 * 16 * 16; i += 256)
        ((float*)s1p)[i] = 0.0f;
    if (tid < 144) w[tid] = conv2_w[oc * 144 + tid];
    __syncthreads();
    for (int i = tid; i < 16 * 196; i += 256) {
        int ic = i / 196, pos = i % 196;
        int yy = pos / 14, xx = pos % 14;
        const float* fp = featr + ((b * 16 + ic) * 784) + (2 * yy) * 28 + 2 * xx;
        s1p[ic][yy + 1][xx + 1] = fmaxf(fmaxf(fp[0], fp[1]), fmaxf(fp[28], fp[29]));
    }
    __syncthreads();

    if (tid < 196) {
        int oh = tid / 14, ow = tid % 14;
        float a0 = 0.0f, a1 = 0.0f, a2 = 0.0f;
#pragma unroll
        for (int ic = 0; ic < 16; ic++) {
            const float* wp = &w[ic * 9];
            const float* sp = &s1p[ic][oh][ow];
            a0 = fmaf(sp[0],  wp[0], fmaf(sp[1],  wp[1], fmaf(sp[2],  wp[2], a0)));
            a1 = fmaf(sp[16], wp[3], fmaf(sp[17], wp[4], fmaf(sp[18], wp[5], a1)));
            a2 = fmaf(sp[32], wp[6], fmaf(sp[33], wp[7], fmaf(sp[34], wp[8], a2)));
        }
        float sc = bn2_g[oc] * rsqrtf(bn2_v[oc] + 1e-5f);
        float shf = bn2_b[oc] - bn2_m[oc] * sc;
        co[tid] = fmaxf((a0 + a1 + a2 + conv2_b[oc]) * sc + shf, 0.0f);
    }
    __syncthreads();

    if (tid < 49) {
        int oh = tid / 7, ow = tid % 7;
        const float* c0 = &co[(2 * oh) * 14 + 2 * ow];
        s2g[((b * 32 + oc) * 49) + tid] =
            fmaxf(fmaxf(c0[0], c0[1]), fmaxf(c0[14], c0[15]));
    }
}

// ---------------- Kernel 4: conv3 + bn3 + relu + pool(7->3) -----------------
// block = (b, oc): 256 blocks x 64 threads. s3g: [B][576] flat [64][3][3]
__global__ void __launch_bounds__(64) conv3_k(
    const float* __restrict__ s2g,
    const float* __restrict__ conv3_w, const float* __restrict__ conv3_b,
    const float* __restrict__ bn3_g, const float* __restrict__ bn3_b,
    const float* __restrict__ bn3_m, const float* __restrict__ bn3_v,
    float* __restrict__ s3g) {
    const int b  = blockIdx.x >> 6;
    const int oc = blockIdx.x & 63;
    const int tid = threadIdx.x;

    __shared__ float s2p[32][9][9];    // padded, 10.1 KB
    __shared__ float w[32 * 9];
    __shared__ float co[49];

    for (int i = tid; i < 32 * 81; i += 64)
        ((float*)s2p)[i] = 0.0f;
    for (int i = tid; i < 288; i += 64) w[i] = conv3_w[oc * 288 + i];
    __syncthreads();
    for (int i = tid; i < 32 * 49; i += 64) {
        int ic = i / 49, pos = i % 49;
        s2p[ic][pos / 7 + 1][pos % 7 + 1] = s2g[((b * 32 + ic) * 49) + pos];
    }
    __syncthreads();

    if (tid < 49) {
        int oh = tid / 7, ow = tid % 7;
        float a0 = 0.0f, a1 = 0.0f, a2 = 0.0f;
#pragma unroll
        for (int ic = 0; ic < 32; ic++) {
            const float* wp = &w[ic * 9];
            const float* sp = &s2p[ic][oh][ow];
            a0 = fmaf(sp[0],  wp[0], fmaf(sp[1],  wp[1], fmaf(sp[2],  wp[2], a0)));
            a1 = fmaf(sp[9],  wp[3], fmaf(sp[10], wp[4], fmaf(sp[11], wp[5], a1)));
            a2 = fmaf(sp[18], wp[6], fmaf(sp[19], wp[7], fmaf(sp[20], wp[8], a2)));
        }
        float sc = bn3_g[oc] * rsqrtf(bn3_v[oc] + 1e-5f);
        float shf = bn3_b[oc] - bn3_m[oc] * sc;
        co[tid] = fmaxf((a0 + a1 + a2 + conv3_b[oc]) * sc + shf, 0.0f);
    }
    __syncthreads();

    if (tid < 9) {
        int oh = tid / 3, ow = tid % 3;
        const float* c0 = &co[(2 * oh) * 7 + 2 * ow];
        s3g[b * 576 + oc * 9 + tid] = fmaxf(fmaxf(c0[0], c0[1]), fmaxf(c0[7], c0[8]));
    }
}

// ---------------- Kernel 5: fc1 + relu + fc2, wave-coalesced ----------------
// 4 blocks x 1024 threads (16 waves: 8 fc1-outputs each; 10 waves do fc2).
__global__ void __launch_bounds__(1024) fc_k(
    const float* __restrict__ s3g,
    const float* __restrict__ fc1_w, const float* __restrict__ fc1_b,
    const float* __restrict__ fc2_w, const float* __restrict__ fc2_b,
    float* __restrict__ out) {
    const int b = blockIdx.x;
    const int tid = threadIdx.x;
    const int wid = tid >> 6, lane = tid & 63;
    __shared__ float s3[576];
    __shared__ float h[128];

    for (int i = tid; i < 576; i += 1024) s3[i] = s3g[b * 576 + i];
    __syncthreads();

#pragma unroll
    for (int oo = 0; oo < 8; oo++) {
        int o = wid * 8 + oo;
        const float* w = fc1_w + o * 576;
        float acc = 0.0f;
#pragma unroll
        for (int jj = 0; jj < 9; jj++)     // lanes across 576: coalesced
            acc = fmaf(s3[jj * 64 + lane], w[jj * 64 + lane], acc);
#pragma unroll
        for (int off = 32; off; off >>= 1) acc += __shfl_down(acc, off);
        if (lane == 0) h[o] = fmaxf(acc + fc1_b[o], 0.0f);
    }
    __syncthreads();

    if (wid < 10) {
        const float* w = fc2_w + wid * 128;
        float acc = fmaf(h[lane], w[lane], 0.0f);
        acc = fmaf(h[64 + lane], w[64 + lane], acc);
#pragma unroll
        for (int off = 32; off; off >>= 1) acc += __shfl_down(acc, off);
        if (lane == 0) out[b * 10 + wid] = acc + fc2_b[wid];
    }
}

extern "C" void kernel_launch(void* const* d_in, const int* in_sizes, int n_in,
                              void* d_out, int out_size, void* d_ws, size_t ws_size,
                              hipStream_t stream) {
    const int*   ct0    = (const int*)d_in[0];
    const int*   cts    = (const int*)d_in[1];
    const int*   y      = (const int*)d_in[2];
    const int*   sk_y   = (const int*)d_in[3];
    const float* bias1  = (const float*)d_in[4];
    const float* bn1_g  = (const float*)d_in[5];
    const float* bn1_b  = (const float*)d_in[6];
    const float* bn1_m  = (const float*)d_in[7];
    const float* bn1_v  = (const float*)d_in[8];
    const float* conv2_w = (const float*)d_in[9];
    const float* conv2_b = (const float*)d_in[10];
    const float* bn2_g  = (const float*)d_in[11];
    const float* bn2_b  = (const float*)d_in[12];
    const float* bn2_m  = (const float*)d_in[13];
    const float* bn2_v  = (const float*)d_in[14];
    const float* conv3_w = (const float*)d_in[15];
    const float* conv3_b = (const float*)d_in[16];
    const float* bn3_g  = (const float*)d_in[17];
    const float* bn3_b  = (const float*)d_in[18];
    const float* bn3_m  = (const float*)d_in[19];
    const float* bn3_v  = (const float*)d_in[20];
    const float* fc1_w  = (const float*)d_in[21];
    const float* fc1_b  = (const float*)d_in[22];
    const float* fc2_w  = (const float*)d_in[23];
    const float* fc2_b  = (const float*)d_in[24];
    const int*   g_in   = (const int*)d_in[25];
    float* out = (float*)d_out;

    // Workspace layout (bytes):
    //   [0,        4000256)  int32 dlog table (p entries)
    //   [4000256,  4200960)  float featr [4][16][28][28]
    //   [4200960,  4226048)  float s2g   [4][32][7][7]
    //   [4226048,  4235264)  float s3g   [4][576]
    char* ws = (char*)d_ws;
    int*   table = (int*)ws;
    float* featr = (float*)(ws + 4000256);
    float* s2g   = (float*)(ws + 4200960);
    float* s3g   = (float*)(ws + 4226048);

    build_table<<<(TBLN + 255) / 256, 256, 0, stream>>>(g_in, table);

    decrypt<<<NDEC / 256, 256, 0, stream>>>(
        ct0, cts, y, sk_y, bias1, bn1_g, bn1_b, bn1_m, bn1_v, table, featr);

    conv2_k<<<BATCH * 32, 256, 0, stream>>>(
        featr, conv2_w, conv2_b, bn2_g, bn2_b, bn2_m, bn2_v, s2g);

    conv3_k<<<BATCH * 64, 64, 0, stream>>>(
        s2g, conv3_w, conv3_b, bn3_g, bn3_b, bn3_m, bn3_v, s3g);

    fc_k<<<BATCH, 1024, 0, stream>>>(s3g, fc1_w, fc1_b, fc2_w, fc2_b, out);
}